// Round 5
// baseline (196.356 us; speedup 1.0000x reference)
//
#include <hip/hip_runtime.h>

// RX(theta) on `qubit` of a [B, 2^nq] complex state (real/imag split, fp32).
//   nr0 = c*r0 + s*i1 ; ni0 = c*i0 - s*r1
//   nr1 = c*r1 + s*i0 ; ni1 = c*i1 - s*r0
// c = cos(theta/2), s = sin(theta/2), pair stride = right = 2^(nq-q-1).
//
// Pure stream: grid-stride persistent kernel (2048 blocks), 4 pairs per
// pair-block (one 16B vector per stream), manual x2 unroll so each thread
// keeps 8 nontemporal loads in flight. 32-bit indexing (n <= 2^31).

typedef float f32x4 __attribute__((ext_vector_type(4)));

__global__ void __launch_bounds__(256)
rx_gate_kernel(const float* __restrict__ sr,
               const float* __restrict__ si,
               const float* __restrict__ theta,
               const int* __restrict__ qubit_p,
               const int* __restrict__ nq_p,
               float* __restrict__ out_r,
               float* __restrict__ out_i,
               unsigned int npairs) {
    const int shift = nq_p[0] - qubit_p[0] - 1;   // log2(right)
    const unsigned int right = 1u << shift;
    const unsigned int mask = right - 1u;

    const float half = 0.5f * theta[0];
    const float c = cosf(half);
    const float s = sinf(half);

    const unsigned int T = gridDim.x * blockDim.x;
    const unsigned int t = blockIdx.x * blockDim.x + threadIdx.x;

    if ((right & 3u) == 0) {
        const unsigned int npb = npairs >> 2;      // pair-blocks of 4 pairs

        unsigned int pb = t;
        // x2-unrolled grid-stride: 8 independent 16B NT loads in flight
        for (; pb + T < npb; pb += 2u * T) {
            const unsigned int pA = pb << 2;
            const unsigned int pB = (pb + T) << 2;
            const unsigned int iA = ((pA >> shift) << (shift + 1)) | (pA & mask);
            const unsigned int iB = ((pB >> shift) << (shift + 1)) | (pB & mask);

            const f32x4 R0a = __builtin_nontemporal_load((const f32x4*)(sr + iA));
            const f32x4 R1a = __builtin_nontemporal_load((const f32x4*)(sr + iA + right));
            const f32x4 I0a = __builtin_nontemporal_load((const f32x4*)(si + iA));
            const f32x4 I1a = __builtin_nontemporal_load((const f32x4*)(si + iA + right));
            const f32x4 R0b = __builtin_nontemporal_load((const f32x4*)(sr + iB));
            const f32x4 R1b = __builtin_nontemporal_load((const f32x4*)(sr + iB + right));
            const f32x4 I0b = __builtin_nontemporal_load((const f32x4*)(si + iB));
            const f32x4 I1b = __builtin_nontemporal_load((const f32x4*)(si + iB + right));

            f32x4 NR0a, NR1a, NI0a, NI1a, NR0b, NR1b, NI0b, NI1b;
#pragma unroll
            for (int k = 0; k < 4; ++k) {
                NR0a[k] = fmaf(c, R0a[k],  s * I1a[k]);
                NI0a[k] = fmaf(c, I0a[k], -s * R1a[k]);
                NR1a[k] = fmaf(c, R1a[k],  s * I0a[k]);
                NI1a[k] = fmaf(c, I1a[k], -s * R0a[k]);
                NR0b[k] = fmaf(c, R0b[k],  s * I1b[k]);
                NI0b[k] = fmaf(c, I0b[k], -s * R1b[k]);
                NR1b[k] = fmaf(c, R1b[k],  s * I0b[k]);
                NI1b[k] = fmaf(c, I1b[k], -s * R0b[k]);
            }

            __builtin_nontemporal_store(NR0a, (f32x4*)(out_r + iA));
            __builtin_nontemporal_store(NR1a, (f32x4*)(out_r + iA + right));
            __builtin_nontemporal_store(NI0a, (f32x4*)(out_i + iA));
            __builtin_nontemporal_store(NI1a, (f32x4*)(out_i + iA + right));
            __builtin_nontemporal_store(NR0b, (f32x4*)(out_r + iB));
            __builtin_nontemporal_store(NR1b, (f32x4*)(out_r + iB + right));
            __builtin_nontemporal_store(NI0b, (f32x4*)(out_i + iB));
            __builtin_nontemporal_store(NI1b, (f32x4*)(out_i + iB + right));
        }
        // leftover single pair-blocks
        for (; pb < npb; pb += T) {
            const unsigned int p = pb << 2;
            const unsigned int idx0 = ((p >> shift) << (shift + 1)) | (p & mask);

            const f32x4 R0 = __builtin_nontemporal_load((const f32x4*)(sr + idx0));
            const f32x4 R1 = __builtin_nontemporal_load((const f32x4*)(sr + idx0 + right));
            const f32x4 I0 = __builtin_nontemporal_load((const f32x4*)(si + idx0));
            const f32x4 I1 = __builtin_nontemporal_load((const f32x4*)(si + idx0 + right));

            f32x4 NR0, NR1, NI0, NI1;
#pragma unroll
            for (int k = 0; k < 4; ++k) {
                NR0[k] = fmaf(c, R0[k],  s * I1[k]);
                NI0[k] = fmaf(c, I0[k], -s * R1[k]);
                NR1[k] = fmaf(c, R1[k],  s * I0[k]);
                NI1[k] = fmaf(c, I1[k], -s * R0[k]);
            }

            __builtin_nontemporal_store(NR0, (f32x4*)(out_r + idx0));
            __builtin_nontemporal_store(NR1, (f32x4*)(out_r + idx0 + right));
            __builtin_nontemporal_store(NI0, (f32x4*)(out_i + idx0));
            __builtin_nontemporal_store(NI1, (f32x4*)(out_i + idx0 + right));
        }
        // remainder pairs (npairs % 4): first few threads, one pair each
        const unsigned int rem0 = npb << 2;
        const unsigned int pk = rem0 + t;
        if (pk < npairs) {
            const unsigned int idx = ((pk >> shift) << (shift + 1)) | (pk & mask);
            const float r0 = sr[idx];
            const float r1 = sr[idx + right];
            const float i0 = si[idx];
            const float i1 = si[idx + right];
            out_r[idx]         = fmaf(c, r0,  s * i1);
            out_i[idx]         = fmaf(c, i0, -s * r1);
            out_r[idx + right] = fmaf(c, r1,  s * i0);
            out_i[idx + right] = fmaf(c, i1, -s * r0);
        }
    } else {
        // right < 4: scalar grid-stride over all pairs
        for (unsigned int pk = t; pk < npairs; pk += T) {
            const unsigned int idx = ((pk >> shift) << (shift + 1)) | (pk & mask);
            const float r0 = sr[idx];
            const float r1 = sr[idx + right];
            const float i0 = si[idx];
            const float i1 = si[idx + right];
            out_r[idx]         = fmaf(c, r0,  s * i1);
            out_i[idx]         = fmaf(c, i0, -s * r1);
            out_r[idx + right] = fmaf(c, r1,  s * i0);
            out_i[idx + right] = fmaf(c, i1, -s * r0);
        }
    }
}

extern "C" void kernel_launch(void* const* d_in, const int* in_sizes, int n_in,
                              void* d_out, int out_size, void* d_ws, size_t ws_size,
                              hipStream_t stream) {
    const float* sr    = (const float*)d_in[0];
    const float* si    = (const float*)d_in[1];
    const float* theta = (const float*)d_in[2];
    const int* qubit_p = (const int*)d_in[3];
    const int* nq_p    = (const int*)d_in[4];

    const long long n = (long long)in_sizes[0];   // B * 2^nq elements per array
    float* out_r = (float*)d_out;
    float* out_i = out_r + n;

    const unsigned int npairs = (unsigned int)(n / 2);
    const unsigned int npb    = npairs >> 2;
    const int block = 256;
    // persistent grid: 256 CU x 8 blocks, grid-stride the rest
    long long need = ((long long)npb + block - 1) / block;
    if (need < 1) need = 1;
    const unsigned int grid = (unsigned int)(need < 2048 ? need : 2048);

    rx_gate_kernel<<<dim3(grid), dim3(block), 0, stream>>>(
        sr, si, theta, qubit_p, nq_p, out_r, out_i, npairs);
}

// Round 6
// 188.710 us; speedup vs baseline: 1.0405x; 1.0405x over previous
//
#include <hip/hip_runtime.h>

// RX(theta) on `qubit` of a [B, 2^nq] complex state (real/imag split, fp32).
//   nr0 = c*r0 + s*i1 ; ni0 = c*i0 - s*r1
//   nr1 = c*r1 + s*i0 ; ni1 = c*i1 - s*r0
// c = cos(theta/2), s = sin(theta/2), pair stride = right = 2^(nq-q-1).
//
// Pure stream: one-shot kernel, 4 pairs/thread (one 16B NT vector per stream
// per thread, perfectly coalesced: 16B/lane at 16B lane stride). block=1024
// so each block covers 64KB contiguous per stream (DRAM row locality across
// the 8 concurrent streams/wave). 32-bit indexing (n <= 2^31).

typedef float f32x4 __attribute__((ext_vector_type(4)));

__global__ void __launch_bounds__(1024)
rx_gate_kernel(const float* __restrict__ sr,
               const float* __restrict__ si,
               const float* __restrict__ theta,
               const int* __restrict__ qubit_p,
               const int* __restrict__ nq_p,
               float* __restrict__ out_r,
               float* __restrict__ out_i,
               unsigned int npairs) {
    const unsigned int t = blockIdx.x * blockDim.x + threadIdx.x;
    const unsigned int p = t * 4u;  // first pair index handled by this thread
    if (p >= npairs) return;

    const int shift = nq_p[0] - qubit_p[0] - 1;   // log2(right)
    const unsigned int right = 1u << shift;
    const unsigned int mask = right - 1u;

    const float half = 0.5f * theta[0];
    const float c = cosf(half);
    const float s = sinf(half);

    if (((right & 3u) == 0) && (p + 4u <= npairs)) {
        // vector path: 4 consecutive pairs, contiguous, 16B-aligned
        const unsigned int idx0 = ((p >> shift) << (shift + 1)) | (p & mask);

        const f32x4 R0 = __builtin_nontemporal_load((const f32x4*)(sr + idx0));
        const f32x4 R1 = __builtin_nontemporal_load((const f32x4*)(sr + idx0 + right));
        const f32x4 I0 = __builtin_nontemporal_load((const f32x4*)(si + idx0));
        const f32x4 I1 = __builtin_nontemporal_load((const f32x4*)(si + idx0 + right));

        f32x4 NR0, NR1, NI0, NI1;
#pragma unroll
        for (int k = 0; k < 4; ++k) {
            NR0[k] = fmaf(c, R0[k],  s * I1[k]);
            NI0[k] = fmaf(c, I0[k], -s * R1[k]);
            NR1[k] = fmaf(c, R1[k],  s * I0[k]);
            NI1[k] = fmaf(c, I1[k], -s * R0[k]);
        }

        __builtin_nontemporal_store(NR0, (f32x4*)(out_r + idx0));
        __builtin_nontemporal_store(NR1, (f32x4*)(out_r + idx0 + right));
        __builtin_nontemporal_store(NI0, (f32x4*)(out_i + idx0));
        __builtin_nontemporal_store(NI1, (f32x4*)(out_i + idx0 + right));
    } else {
        // scalar fallback (tail, or right < 4)
        for (unsigned int k = 0; k < 4u; ++k) {
            const unsigned int pk = p + k;
            if (pk >= npairs) break;
            const unsigned int idx = ((pk >> shift) << (shift + 1)) | (pk & mask);
            const float r0 = sr[idx];
            const float r1 = sr[idx + right];
            const float i0 = si[idx];
            const float i1 = si[idx + right];
            out_r[idx]         = fmaf(c, r0,  s * i1);
            out_i[idx]         = fmaf(c, i0, -s * r1);
            out_r[idx + right] = fmaf(c, r1,  s * i0);
            out_i[idx + right] = fmaf(c, i1, -s * r0);
        }
    }
}

extern "C" void kernel_launch(void* const* d_in, const int* in_sizes, int n_in,
                              void* d_out, int out_size, void* d_ws, size_t ws_size,
                              hipStream_t stream) {
    const float* sr    = (const float*)d_in[0];
    const float* si    = (const float*)d_in[1];
    const float* theta = (const float*)d_in[2];
    const int* qubit_p = (const int*)d_in[3];
    const int* nq_p    = (const int*)d_in[4];

    const long long n = (long long)in_sizes[0];   // B * 2^nq elements per array
    float* out_r = (float*)d_out;
    float* out_i = out_r + n;

    const unsigned int npairs   = (unsigned int)(n / 2);
    const unsigned int nthreads = (npairs + 3u) / 4u;
    const int block = 1024;
    const unsigned int grid = (nthreads + block - 1) / block;

    rx_gate_kernel<<<dim3(grid), dim3(block), 0, stream>>>(
        sr, si, theta, qubit_p, nq_p, out_r, out_i, npairs);
}